// Round 1
// baseline (5509.124 us; speedup 1.0000x reference)
//
#include <hip/hip_runtime.h>
#include <hip/hip_bf16.h>

#define SELU_LAM   1.0507009873554805f
#define SELU_ALPHA 1.6732632423543772f

__device__ __forceinline__ float selu_f(float v) {
    return v > 0.0f ? SELU_LAM * v
                    : (SELU_LAM * SELU_ALPHA) * (expf(v) - 1.0f);
}

// out = x  (residual init for the scatter-add accumulation)
__global__ __launch_bounds__(256) void copy_kernel(const float4* __restrict__ src,
                                                   float4* __restrict__ dst, int n4) {
    int i = blockIdx.x * 256 + threadIdx.x;
    if (i < n4) dst[i] = src[i];
}

// agg[dst] += x[src] * w  — 32 lanes per edge, one float4 per lane
__global__ __launch_bounds__(256) void scatter_kernel(
    const float*  __restrict__ x,
    const int*    __restrict__ esrc,
    const int*    __restrict__ edst,
    const float*  __restrict__ ew,
    float*        __restrict__ agg,
    int E)
{
    int e = blockIdx.x * 8 + (threadIdx.x >> 5);
    if (e >= E) return;
    int lane = threadIdx.x & 31;
    int s = esrc[e];
    int d = edst[e];
    float w = ew[e];
    float4 v = ((const float4*)(x + (size_t)s * 128))[lane];
    float* dp = agg + (size_t)d * 128 + lane * 4;
    atomicAdd(dp + 0, v.x * w);
    atomicAdd(dp + 1, v.y * w);
    atomicAdd(dp + 2, v.z * w);
    atomicAdd(dp + 3, v.w * w);
}

// out[r,:] = selu(in[r,:] @ W + b)   (W is [128][128] row-major, out = in @ W)
// 32 rows per block, 256 threads, 4 rows x 4 cols per thread. Safe in-place
// (block stages its own rows in LDS before any global write).
__global__ __launch_bounds__(256) void gemm_bias_selu(
    const float* __restrict__ inp,
    const float* __restrict__ W,
    const float* __restrict__ bias,
    float*       __restrict__ outp,
    int nrows)
{
    __shared__ float sW[128 * 128];   // 64 KB
    __shared__ float sH[32 * 128];    // 16 KB

    float4* sW4 = (float4*)sW;
    float4* sH4 = (float4*)sH;

    for (int i = threadIdx.x; i < 128 * 32; i += 256)
        sW4[i] = ((const float4*)W)[i];

    int row0 = blockIdx.x * 32;
    for (int i = threadIdx.x; i < 32 * 32; i += 256) {
        int r = row0 + (i >> 5);
        sH4[i] = (r < nrows) ? ((const float4*)inp)[(size_t)r * 32 + (i & 31)]
                             : make_float4(0.f, 0.f, 0.f, 0.f);
    }
    __syncthreads();

    int cg = threadIdx.x & 31;          // float4 column group: cols [4cg, 4cg+4)
    int rg = (threadIdx.x >> 5) << 2;   // starting row within tile: 0,4,...,28

    float4 acc[4];
    #pragma unroll
    for (int r = 0; r < 4; ++r) acc[r] = make_float4(0.f, 0.f, 0.f, 0.f);

    #pragma unroll 4
    for (int k4 = 0; k4 < 32; ++k4) {
        float4 w0 = sW4[(k4 * 4 + 0) * 32 + cg];
        float4 w1 = sW4[(k4 * 4 + 1) * 32 + cg];
        float4 w2 = sW4[(k4 * 4 + 2) * 32 + cg];
        float4 w3 = sW4[(k4 * 4 + 3) * 32 + cg];
        #pragma unroll
        for (int r = 0; r < 4; ++r) {
            float4 h = sH4[(rg + r) * 32 + k4];
            acc[r].x = fmaf(h.x, w0.x, fmaf(h.y, w1.x, fmaf(h.z, w2.x, fmaf(h.w, w3.x, acc[r].x))));
            acc[r].y = fmaf(h.x, w0.y, fmaf(h.y, w1.y, fmaf(h.z, w2.y, fmaf(h.w, w3.y, acc[r].y))));
            acc[r].z = fmaf(h.x, w0.z, fmaf(h.y, w1.z, fmaf(h.z, w2.z, fmaf(h.w, w3.z, acc[r].z))));
            acc[r].w = fmaf(h.x, w0.w, fmaf(h.y, w1.w, fmaf(h.z, w2.w, fmaf(h.w, w3.w, acc[r].w))));
        }
    }

    float4 bv = ((const float4*)bias)[cg];
    #pragma unroll
    for (int r = 0; r < 4; ++r) {
        int row = row0 + rg + r;
        if (row < nrows) {
            float4 o;
            o.x = selu_f(acc[r].x + bv.x);
            o.y = selu_f(acc[r].y + bv.y);
            o.z = selu_f(acc[r].z + bv.z);
            o.w = selu_f(acc[r].w + bv.w);
            ((float4*)outp)[(size_t)row * 32 + cg] = o;
        }
    }
}

extern "C" void kernel_launch(void* const* d_in, const int* in_sizes, int n_in,
                              void* d_out, int out_size, void* d_ws, size_t ws_size,
                              hipStream_t stream) {
    (void)n_in; (void)d_ws; (void)ws_size; (void)out_size;
    const float* x    = (const float*)d_in[0];
    const int*   esrc = (const int*)  d_in[1];
    const int*   edst = (const int*)  d_in[2];
    const float* ew   = (const float*)d_in[3];
    const float* W1   = (const float*)d_in[4];
    const float* b1   = (const float*)d_in[5];
    const float* W2   = (const float*)d_in[6];
    const float* b2   = (const float*)d_in[7];
    float* out = (float*)d_out;

    int N = in_sizes[0] / 128;
    int E = in_sizes[1];

    // 1) out = x  (residual baked into the accumulator)
    int n4 = N * 32;
    copy_kernel<<<(n4 + 255) / 256, 256, 0, stream>>>((const float4*)x, (float4*)out, n4);

    // 2) out += scatter-add of x[src]*w at dst
    scatter_kernel<<<(E + 7) / 8, 256, 0, stream>>>(x, esrc, edst, ew, out, E);

    // 3) two dense layers, in place
    int gblocks = (N + 31) / 32;
    gemm_bias_selu<<<gblocks, 256, 0, stream>>>(out, W1, b1, out, N);
    gemm_bias_selu<<<gblocks, 256, 0, stream>>>(out, W2, b2, out, N);
}

// Round 2
// 800.643 us; speedup vs baseline: 6.8809x; 6.8809x over previous
//
#include <hip/hip_runtime.h>
#include <hip/hip_bf16.h>

#define SELU_LAM   1.0507009873554805f
#define SELU_ALPHA 1.6732632423543772f

__device__ __forceinline__ float selu_f(float v) {
    return v > 0.0f ? SELU_LAM * v
                    : (SELU_LAM * SELU_ALPHA) * (expf(v) - 1.0f);
}

// ---------------------------------------------------------------- CSR build

// cnt[dst]++ over all edges
__global__ __launch_bounds__(256) void hist_kernel(const int* __restrict__ edst,
                                                   int* __restrict__ cnt, int E) {
    int i = blockIdx.x * 256 + threadIdx.x;
    int stride = gridDim.x * 256;
    for (; i < E; i += stride) atomicAdd(&cnt[edst[i]], 1);
}

// per-1024-chunk sums
__global__ __launch_bounds__(256) void scan_p1(const int* __restrict__ cnt,
                                               int* __restrict__ bsum, int N) {
    __shared__ int red[256];
    int b = blockIdx.x, t = threadIdx.x;
    int base = b * 1024 + t * 4;
    int s = 0;
    #pragma unroll
    for (int i = 0; i < 4; ++i) { int idx = base + i; s += (idx < N) ? cnt[idx] : 0; }
    red[t] = s; __syncthreads();
    for (int d = 128; d > 0; d >>= 1) { if (t < d) red[t] += red[t + d]; __syncthreads(); }
    if (t == 0) bsum[b] = red[0];
}

// exclusive scan of chunk sums (nb <= 1024), single block
__global__ __launch_bounds__(1024) void scan_p2(int* __restrict__ bsum, int nb) {
    __shared__ int buf[1024];
    int t = threadIdx.x;
    buf[t] = (t < nb) ? bsum[t] : 0; __syncthreads();
    for (int d = 1; d < 1024; d <<= 1) {
        int v = (t >= d) ? buf[t - d] : 0; __syncthreads();
        buf[t] += v; __syncthreads();
    }
    if (t < nb) bsum[t] = (t == 0) ? 0 : buf[t - 1];
}

// exclusive scan within chunk + chunk offset (in-place safe: off may == cnt)
__global__ __launch_bounds__(256) void scan_p3(const int* __restrict__ cnt,
                                               const int* __restrict__ bsum,
                                               int* __restrict__ off, int N) {
    __shared__ int lsum[256];
    int b = blockIdx.x, t = threadIdx.x;
    int base = b * 1024 + t * 4;
    int v[4];
    #pragma unroll
    for (int i = 0; i < 4; ++i) { int idx = base + i; v[i] = (idx < N) ? cnt[idx] : 0; }
    lsum[t] = v[0] + v[1] + v[2] + v[3]; __syncthreads();
    for (int d = 1; d < 256; d <<= 1) {
        int val = (t >= d) ? lsum[t - d] : 0; __syncthreads();
        lsum[t] += val; __syncthreads();
    }
    int run = (t == 0 ? 0 : lsum[t - 1]) + bsum[b];
    #pragma unroll
    for (int i = 0; i < 4; ++i) { int idx = base + i; if (idx < N) off[idx] = run; run += v[i]; }
}

// place (src,w) into CSR slots; off[d] becomes end-pointer of segment d
__global__ __launch_bounds__(256) void scatter_build(const int* __restrict__ esrc,
                                                     const int* __restrict__ edst,
                                                     const float* __restrict__ ew,
                                                     int* __restrict__ off,
                                                     int* __restrict__ ssrc,
                                                     float* __restrict__ sw, int E) {
    int i = blockIdx.x * 256 + threadIdx.x;
    int stride = gridDim.x * 256;
    for (; i < E; i += stride) {
        int d = edst[i];
        int p = atomicAdd(&off[d], 1);
        ssrc[p] = esrc[i];
        sw[p]   = ew[i];
    }
}

// one 64-lane wave per dst node; acc = x[node] + sum_e x[src_e]*w_e
__global__ __launch_bounds__(256) void gather_kernel(const float* __restrict__ x,
                                                     const int* __restrict__ endptr,
                                                     const int* __restrict__ ssrc,
                                                     const float* __restrict__ sw,
                                                     float* __restrict__ out, int N) {
    int node = blockIdx.x * 4 + (threadIdx.x >> 6);
    if (node >= N) return;
    int lane = threadIdx.x & 63;
    int beg = (node == 0) ? 0 : endptr[node - 1];
    int end = endptr[node];

    float2 acc = ((const float2*)(x + (size_t)node * 128))[lane];  // residual

    int e = beg;
    for (; e + 1 < end; e += 2) {
        int   s0 = ssrc[e],   s1 = ssrc[e + 1];
        float w0 = sw[e],     w1 = sw[e + 1];
        float2 v0 = ((const float2*)(x + (size_t)s0 * 128))[lane];
        float2 v1 = ((const float2*)(x + (size_t)s1 * 128))[lane];
        acc.x = fmaf(v0.x, w0, acc.x); acc.y = fmaf(v0.y, w0, acc.y);
        acc.x = fmaf(v1.x, w1, acc.x); acc.y = fmaf(v1.y, w1, acc.y);
    }
    if (e < end) {
        int s0 = ssrc[e]; float w0 = sw[e];
        float2 v0 = ((const float2*)(x + (size_t)s0 * 128))[lane];
        acc.x = fmaf(v0.x, w0, acc.x); acc.y = fmaf(v0.y, w0, acc.y);
    }
    ((float2*)(out + (size_t)node * 128))[lane] = acc;
}

// ------------------------------------------------- fallback atomic path

__global__ __launch_bounds__(256) void copy_kernel(const float4* __restrict__ src,
                                                   float4* __restrict__ dst, int n4) {
    int i = blockIdx.x * 256 + threadIdx.x;
    if (i < n4) dst[i] = src[i];
}

__global__ __launch_bounds__(256) void scatter_kernel(const float* __restrict__ x,
                                                      const int* __restrict__ esrc,
                                                      const int* __restrict__ edst,
                                                      const float* __restrict__ ew,
                                                      float* __restrict__ agg, int E) {
    int e = blockIdx.x * 8 + (threadIdx.x >> 5);
    if (e >= E) return;
    int lane = threadIdx.x & 31;
    int s = esrc[e];
    int d = edst[e];
    float w = ew[e];
    float4 v = ((const float4*)(x + (size_t)s * 128))[lane];
    float* dp = agg + (size_t)d * 128 + lane * 4;
    atomicAdd(dp + 0, v.x * w);
    atomicAdd(dp + 1, v.y * w);
    atomicAdd(dp + 2, v.z * w);
    atomicAdd(dp + 3, v.w * w);
}

// ----------------------------------------------------------------- GEMM

// out[r,:] = selu(in[r,:] @ W + b); W [128][128] row-major; in-place safe.
__global__ __launch_bounds__(256) void gemm_bias_selu(const float* __restrict__ inp,
                                                      const float* __restrict__ W,
                                                      const float* __restrict__ bias,
                                                      float* __restrict__ outp, int nrows) {
    __shared__ float sW[128 * 128];
    __shared__ float sH[32 * 128];

    float4* sW4 = (float4*)sW;
    float4* sH4 = (float4*)sH;

    for (int i = threadIdx.x; i < 128 * 32; i += 256)
        sW4[i] = ((const float4*)W)[i];

    int row0 = blockIdx.x * 32;
    for (int i = threadIdx.x; i < 32 * 32; i += 256) {
        int r = row0 + (i >> 5);
        sH4[i] = (r < nrows) ? ((const float4*)inp)[(size_t)r * 32 + (i & 31)]
                             : make_float4(0.f, 0.f, 0.f, 0.f);
    }
    __syncthreads();

    int cg = threadIdx.x & 31;
    int rg = (threadIdx.x >> 5) << 2;

    float4 acc[4];
    #pragma unroll
    for (int r = 0; r < 4; ++r) acc[r] = make_float4(0.f, 0.f, 0.f, 0.f);

    #pragma unroll 4
    for (int k4 = 0; k4 < 32; ++k4) {
        float4 w0 = sW4[(k4 * 4 + 0) * 32 + cg];
        float4 w1 = sW4[(k4 * 4 + 1) * 32 + cg];
        float4 w2 = sW4[(k4 * 4 + 2) * 32 + cg];
        float4 w3 = sW4[(k4 * 4 + 3) * 32 + cg];
        #pragma unroll
        for (int r = 0; r < 4; ++r) {
            float4 h = sH4[(rg + r) * 32 + k4];
            acc[r].x = fmaf(h.x, w0.x, fmaf(h.y, w1.x, fmaf(h.z, w2.x, fmaf(h.w, w3.x, acc[r].x))));
            acc[r].y = fmaf(h.x, w0.y, fmaf(h.y, w1.y, fmaf(h.z, w2.y, fmaf(h.w, w3.y, acc[r].y))));
            acc[r].z = fmaf(h.x, w0.z, fmaf(h.y, w1.z, fmaf(h.z, w2.z, fmaf(h.w, w3.z, acc[r].z))));
            acc[r].w = fmaf(h.x, w0.w, fmaf(h.y, w1.w, fmaf(h.z, w2.w, fmaf(h.w, w3.w, acc[r].w))));
        }
    }

    float4 bv = ((const float4*)bias)[cg];
    #pragma unroll
    for (int r = 0; r < 4; ++r) {
        int row = row0 + rg + r;
        if (row < nrows) {
            float4 o;
            o.x = selu_f(acc[r].x + bv.x);
            o.y = selu_f(acc[r].y + bv.y);
            o.z = selu_f(acc[r].z + bv.z);
            o.w = selu_f(acc[r].w + bv.w);
            ((float4*)outp)[(size_t)row * 32 + cg] = o;
        }
    }
}

// ---------------------------------------------------------------- launch

extern "C" void kernel_launch(void* const* d_in, const int* in_sizes, int n_in,
                              void* d_out, int out_size, void* d_ws, size_t ws_size,
                              hipStream_t stream) {
    (void)n_in; (void)out_size;
    const float* x    = (const float*)d_in[0];
    const int*   esrc = (const int*)  d_in[1];
    const int*   edst = (const int*)  d_in[2];
    const float* ew   = (const float*)d_in[3];
    const float* W1   = (const float*)d_in[4];
    const float* b1   = (const float*)d_in[5];
    const float* W2   = (const float*)d_in[6];
    const float* b2   = (const float*)d_in[7];
    float* out = (float*)d_out;

    int N = in_sizes[0] / 128;
    int E = in_sizes[1];
    int nb = (N + 1023) / 1024;   // scan chunks

    size_t need = ((size_t)N + 2 * (size_t)E + (size_t)nb) * 4;

    if (ws_size >= need && nb <= 1024) {
        // ---- CSR path ----
        int*   off  = (int*)d_ws;            // N ints: counts -> offsets -> end-ptrs
        int*   ssrc = off + N;               // E ints
        float* sw   = (float*)(ssrc + E);    // E floats
        int*   bsum = (int*)(sw + E);        // nb ints

        hipMemsetAsync(off, 0, (size_t)N * 4, stream);

        int hb = (E + 255) / 256; if (hb > 2048) hb = 2048;
        hist_kernel<<<hb, 256, 0, stream>>>(edst, off, E);

        scan_p1<<<nb, 256, 0, stream>>>(off, bsum, N);
        scan_p2<<<1, 1024, 0, stream>>>(bsum, nb);
        scan_p3<<<nb, 256, 0, stream>>>(off, bsum, off, N);

        scatter_build<<<hb, 256, 0, stream>>>(esrc, edst, ew, off, ssrc, sw, E);

        int gb = (N + 3) / 4;
        gather_kernel<<<gb, 256, 0, stream>>>(x, off, ssrc, sw, out, N);
    } else {
        // ---- fallback: atomic scatter ----
        int n4 = N * 32;
        copy_kernel<<<(n4 + 255) / 256, 256, 0, stream>>>((const float4*)x, (float4*)out, n4);
        scatter_kernel<<<(E + 7) / 8, 256, 0, stream>>>(x, esrc, edst, ew, out, E);
    }

    // ---- dense layers, in place ----
    int gblocks = (N + 31) / 32;
    gemm_bias_selu<<<gblocks, 256, 0, stream>>>(out, W1, b1, out, N);
    gemm_bias_selu<<<gblocks, 256, 0, stream>>>(out, W2, b2, out, N);
}

// Round 3
// 767.215 us; speedup vs baseline: 7.1807x; 1.0436x over previous
//
#include <hip/hip_runtime.h>
#include <hip/hip_bf16.h>

#define SELU_LAM   1.0507009873554805f
#define SELU_ALPHA 1.6732632423543772f

__device__ __forceinline__ float selu_f(float v) {
    return v > 0.0f ? SELU_LAM * v
                    : (SELU_LAM * SELU_ALPHA) * (expf(v) - 1.0f);
}

// ---------------------------------------------------------------- CSR build

// cnt[dst]++ over all edges (vectorized edge reads)
__global__ __launch_bounds__(256) void hist_kernel(const int* __restrict__ edst,
                                                   int* __restrict__ cnt, int E) {
    int tid = blockIdx.x * 256 + threadIdx.x;
    int stride = gridDim.x * 256;
    int n4 = E >> 2;
    for (int j = tid; j < n4; j += stride) {
        int4 d = ((const int4*)edst)[j];
        atomicAdd(&cnt[d.x], 1);
        atomicAdd(&cnt[d.y], 1);
        atomicAdd(&cnt[d.z], 1);
        atomicAdd(&cnt[d.w], 1);
    }
    for (int j = (n4 << 2) + tid; j < E; j += stride) atomicAdd(&cnt[edst[j]], 1);
}

// per-1024-chunk sums
__global__ __launch_bounds__(256) void scan_p1(const int* __restrict__ cnt,
                                               int* __restrict__ bsum, int N) {
    __shared__ int red[256];
    int b = blockIdx.x, t = threadIdx.x;
    int base = b * 1024 + t * 4;
    int s = 0;
    #pragma unroll
    for (int i = 0; i < 4; ++i) { int idx = base + i; s += (idx < N) ? cnt[idx] : 0; }
    red[t] = s; __syncthreads();
    for (int d = 128; d > 0; d >>= 1) { if (t < d) red[t] += red[t + d]; __syncthreads(); }
    if (t == 0) bsum[b] = red[0];
}

// exclusive scan of chunk sums (nb <= 1024), single block
__global__ __launch_bounds__(1024) void scan_p2(int* __restrict__ bsum, int nb) {
    __shared__ int buf[1024];
    int t = threadIdx.x;
    buf[t] = (t < nb) ? bsum[t] : 0; __syncthreads();
    for (int d = 1; d < 1024; d <<= 1) {
        int v = (t >= d) ? buf[t - d] : 0; __syncthreads();
        buf[t] += v; __syncthreads();
    }
    if (t < nb) bsum[t] = (t == 0) ? 0 : buf[t - 1];
}

// exclusive scan within chunk + chunk offset (in-place safe: off may == cnt)
__global__ __launch_bounds__(256) void scan_p3(const int* __restrict__ cnt,
                                               const int* __restrict__ bsum,
                                               int* __restrict__ off, int N) {
    __shared__ int lsum[256];
    int b = blockIdx.x, t = threadIdx.x;
    int base = b * 1024 + t * 4;
    int v[4];
    #pragma unroll
    for (int i = 0; i < 4; ++i) { int idx = base + i; v[i] = (idx < N) ? cnt[idx] : 0; }
    lsum[t] = v[0] + v[1] + v[2] + v[3]; __syncthreads();
    for (int d = 1; d < 256; d <<= 1) {
        int val = (t >= d) ? lsum[t - d] : 0; __syncthreads();
        lsum[t] += val; __syncthreads();
    }
    int run = (t == 0 ? 0 : lsum[t - 1]) + bsum[b];
    #pragma unroll
    for (int i = 0; i < 4; ++i) { int idx = base + i; if (idx < N) off[idx] = run; run += v[i]; }
}

// place packed (src, w) into CSR slots; off[d] becomes end-pointer of segment d
__global__ __launch_bounds__(256) void scatter_build(const int* __restrict__ esrc,
                                                     const int* __restrict__ edst,
                                                     const float* __restrict__ ew,
                                                     int* __restrict__ off,
                                                     int2* __restrict__ csr, int E) {
    int tid = blockIdx.x * 256 + threadIdx.x;
    int stride = gridDim.x * 256;
    int n4 = E >> 2;
    for (int j = tid; j < n4; j += stride) {
        int4   s = ((const int4*)esrc)[j];
        int4   d = ((const int4*)edst)[j];
        float4 w = ((const float4*)ew)[j];
        int p;
        p = atomicAdd(&off[d.x], 1); csr[p] = make_int2(s.x, __float_as_int(w.x));
        p = atomicAdd(&off[d.y], 1); csr[p] = make_int2(s.y, __float_as_int(w.y));
        p = atomicAdd(&off[d.z], 1); csr[p] = make_int2(s.z, __float_as_int(w.z));
        p = atomicAdd(&off[d.w], 1); csr[p] = make_int2(s.w, __float_as_int(w.w));
    }
    for (int j = (n4 << 2) + tid; j < E; j += stride) {
        int p = atomicAdd(&off[edst[j]], 1);
        csr[p] = make_int2(esrc[j], __float_as_int(ew[j]));
    }
}

// one 64-lane wave per dst node, split into two 32-lane halves each owning a
// full 512B row per edge; 2-edge unroll per half => 4 loads in flight.
__global__ __launch_bounds__(256) void gather_kernel(const float* __restrict__ x,
                                                     const int* __restrict__ endptr,
                                                     const int2* __restrict__ csr,
                                                     float* __restrict__ out, int N) {
    int node = blockIdx.x * 4 + (threadIdx.x >> 6);
    if (node >= N) return;
    int lane = threadIdx.x & 63;
    int half = lane >> 5;
    int cg   = lane & 31;
    int beg = (node == 0) ? 0 : endptr[node - 1];
    int end = endptr[node];

    const float4* xr = (const float4*)(x + (size_t)node * 128);
    float4 res = xr[cg];
    float4 acc = half ? make_float4(0.f, 0.f, 0.f, 0.f) : res;

    int e = beg + half;
    for (; e + 2 < end; e += 4) {
        int2 d0 = csr[e];
        int2 d1 = csr[e + 2];
        float w0 = __int_as_float(d0.y);
        float w1 = __int_as_float(d1.y);
        float4 v0 = ((const float4*)(x + (size_t)d0.x * 128))[cg];
        float4 v1 = ((const float4*)(x + (size_t)d1.x * 128))[cg];
        acc.x = fmaf(v0.x, w0, acc.x); acc.y = fmaf(v0.y, w0, acc.y);
        acc.z = fmaf(v0.z, w0, acc.z); acc.w = fmaf(v0.w, w0, acc.w);
        acc.x = fmaf(v1.x, w1, acc.x); acc.y = fmaf(v1.y, w1, acc.y);
        acc.z = fmaf(v1.z, w1, acc.z); acc.w = fmaf(v1.w, w1, acc.w);
    }
    if (e < end) {
        int2 d0 = csr[e];
        float w0 = __int_as_float(d0.y);
        float4 v0 = ((const float4*)(x + (size_t)d0.x * 128))[cg];
        acc.x = fmaf(v0.x, w0, acc.x); acc.y = fmaf(v0.y, w0, acc.y);
        acc.z = fmaf(v0.z, w0, acc.z); acc.w = fmaf(v0.w, w0, acc.w);
    }

    // combine halves
    acc.x += __shfl_xor(acc.x, 32);
    acc.y += __shfl_xor(acc.y, 32);
    acc.z += __shfl_xor(acc.z, 32);
    acc.w += __shfl_xor(acc.w, 32);

    if (half == 0)
        ((float4*)(out + (size_t)node * 128))[cg] = acc;
}

// ------------------------------------------------- fallback atomic path

__global__ __launch_bounds__(256) void copy_kernel(const float4* __restrict__ src,
                                                   float4* __restrict__ dst, int n4) {
    int i = blockIdx.x * 256 + threadIdx.x;
    if (i < n4) dst[i] = src[i];
}

__global__ __launch_bounds__(256) void scatter_kernel(const float* __restrict__ x,
                                                      const int* __restrict__ esrc,
                                                      const int* __restrict__ edst,
                                                      const float* __restrict__ ew,
                                                      float* __restrict__ agg, int E) {
    int e = blockIdx.x * 8 + (threadIdx.x >> 5);
    if (e >= E) return;
    int lane = threadIdx.x & 31;
    int s = esrc[e];
    int d = edst[e];
    float w = ew[e];
    float4 v = ((const float4*)(x + (size_t)s * 128))[lane];
    float* dp = agg + (size_t)d * 128 + lane * 4;
    atomicAdd(dp + 0, v.x * w);
    atomicAdd(dp + 1, v.y * w);
    atomicAdd(dp + 2, v.z * w);
    atomicAdd(dp + 3, v.w * w);
}

// ----------------------------------------------------------------- GEMM

// out[r,:] = selu(in[r,:] @ W + b); W [128][128] row-major; in-place safe.
__global__ __launch_bounds__(256) void gemm_bias_selu(const float* __restrict__ inp,
                                                      const float* __restrict__ W,
                                                      const float* __restrict__ bias,
                                                      float* __restrict__ outp, int nrows) {
    __shared__ float sW[128 * 128];
    __shared__ float sH[32 * 128];

    float4* sW4 = (float4*)sW;
    float4* sH4 = (float4*)sH;

    for (int i = threadIdx.x; i < 128 * 32; i += 256)
        sW4[i] = ((const float4*)W)[i];

    int row0 = blockIdx.x * 32;
    for (int i = threadIdx.x; i < 32 * 32; i += 256) {
        int r = row0 + (i >> 5);
        sH4[i] = (r < nrows) ? ((const float4*)inp)[(size_t)r * 32 + (i & 31)]
                             : make_float4(0.f, 0.f, 0.f, 0.f);
    }
    __syncthreads();

    int cg = threadIdx.x & 31;
    int rg = (threadIdx.x >> 5) << 2;

    float4 acc[4];
    #pragma unroll
    for (int r = 0; r < 4; ++r) acc[r] = make_float4(0.f, 0.f, 0.f, 0.f);

    #pragma unroll 4
    for (int k4 = 0; k4 < 32; ++k4) {
        float4 w0 = sW4[(k4 * 4 + 0) * 32 + cg];
        float4 w1 = sW4[(k4 * 4 + 1) * 32 + cg];
        float4 w2 = sW4[(k4 * 4 + 2) * 32 + cg];
        float4 w3 = sW4[(k4 * 4 + 3) * 32 + cg];
        #pragma unroll
        for (int r = 0; r < 4; ++r) {
            float4 h = sH4[(rg + r) * 32 + k4];
            acc[r].x = fmaf(h.x, w0.x, fmaf(h.y, w1.x, fmaf(h.z, w2.x, fmaf(h.w, w3.x, acc[r].x))));
            acc[r].y = fmaf(h.x, w0.y, fmaf(h.y, w1.y, fmaf(h.z, w2.y, fmaf(h.w, w3.y, acc[r].y))));
            acc[r].z = fmaf(h.x, w0.z, fmaf(h.y, w1.z, fmaf(h.z, w2.z, fmaf(h.w, w3.z, acc[r].z))));
            acc[r].w = fmaf(h.x, w0.w, fmaf(h.y, w1.w, fmaf(h.z, w2.w, fmaf(h.w, w3.w, acc[r].w))));
        }
    }

    float4 bv = ((const float4*)bias)[cg];
    #pragma unroll
    for (int r = 0; r < 4; ++r) {
        int row = row0 + rg + r;
        if (row < nrows) {
            float4 o;
            o.x = selu_f(acc[r].x + bv.x);
            o.y = selu_f(acc[r].y + bv.y);
            o.z = selu_f(acc[r].z + bv.z);
            o.w = selu_f(acc[r].w + bv.w);
            ((float4*)outp)[(size_t)row * 32 + cg] = o;
        }
    }
}

// ---------------------------------------------------------------- launch

extern "C" void kernel_launch(void* const* d_in, const int* in_sizes, int n_in,
                              void* d_out, int out_size, void* d_ws, size_t ws_size,
                              hipStream_t stream) {
    (void)n_in; (void)out_size;
    const float* x    = (const float*)d_in[0];
    const int*   esrc = (const int*)  d_in[1];
    const int*   edst = (const int*)  d_in[2];
    const float* ew   = (const float*)d_in[3];
    const float* W1   = (const float*)d_in[4];
    const float* b1   = (const float*)d_in[5];
    const float* W2   = (const float*)d_in[6];
    const float* b2   = (const float*)d_in[7];
    float* out = (float*)d_out;

    int N = in_sizes[0] / 128;
    int E = in_sizes[1];
    int nb = (N + 1023) / 1024;   // scan chunks

    // layout: off (N ints) | csr (E int2) | bsum (nb ints)
    size_t off_bytes = ((size_t)N * 4 + 7) & ~(size_t)7;   // 8B-align csr
    size_t need = off_bytes + (size_t)E * 8 + (size_t)nb * 4;

    if (ws_size >= need && nb <= 1024) {
        // ---- CSR path ----
        int*  off  = (int*)d_ws;
        int2* csr  = (int2*)((char*)d_ws + off_bytes);
        int*  bsum = (int*)(csr + E);

        hipMemsetAsync(off, 0, (size_t)N * 4, stream);

        int hb = (E / 4 + 255) / 256; if (hb > 2048) hb = 2048;
        hist_kernel<<<hb, 256, 0, stream>>>(edst, off, E);

        scan_p1<<<nb, 256, 0, stream>>>(off, bsum, N);
        scan_p2<<<1, 1024, 0, stream>>>(bsum, nb);
        scan_p3<<<nb, 256, 0, stream>>>(off, bsum, off, N);

        scatter_build<<<hb, 256, 0, stream>>>(esrc, edst, ew, off, csr, E);

        int gb = (N + 3) / 4;
        gather_kernel<<<gb, 256, 0, stream>>>(x, off, csr, out, N);
    } else {
        // ---- fallback: atomic scatter ----
        int n4 = N * 32;
        copy_kernel<<<(n4 + 255) / 256, 256, 0, stream>>>((const float4*)x, (float4*)out, n4);
        scatter_kernel<<<(E + 7) / 8, 256, 0, stream>>>(x, esrc, edst, ew, out, E);
    }

    // ---- dense layers, in place ----
    int gblocks = (N + 31) / 32;
    gemm_bias_selu<<<gblocks, 256, 0, stream>>>(out, W1, b1, out, N);
    gemm_bias_selu<<<gblocks, 256, 0, stream>>>(out, W2, b2, out, N);
}